// Round 14
// baseline (169.287 us; speedup 1.0000x reference)
//
#include <hip/hip_runtime.h>
#include <hip/hip_bf16.h>

// Problem constants
#define Bb   2
#define Nn   512
#define Cc   384
#define Hh   12
#define BN   1024          // B*N
#define NC1  1584          // 3*384 + 3*144 concatenated proj cols
#define CT1  99            // 1584/16 col-tiles
#define SCALE 0.17677669529663687f   // 32^-0.5

typedef __attribute__((ext_vector_type(8))) short short8;
typedef __attribute__((ext_vector_type(4))) float f32x4;

__device__ __forceinline__ unsigned short f2bf(float f){
  union { float f; unsigned u; } v; v.f = f;
  unsigned u = v.u;
  unsigned r = u + 0x7fffu + ((u >> 16) & 1u);
  return (unsigned short)(r >> 16);
}
__device__ __forceinline__ float bf_lo(unsigned u){ union{unsigned u; float f;} v; v.u = u << 16; return v.f; }
__device__ __forceinline__ float bf_hi(unsigned u){ union{unsigned u; float f;} v; v.u = u & 0xffff0000u; return v.f; }
__device__ __forceinline__ unsigned pack2(float a, float b){
  return (unsigned)f2bf(a) | ((unsigned)f2bf(b) << 16);
}

// --------------------- bias tile job: 16i x 32j, LDS-staged coalesced writes
// lds: unsigned short [16][17][36]  (19584 B)
__device__ __forceinline__ void bias_job16(const float* __restrict__ pair,
    const float* __restrict__ Wpb, const float* __restrict__ bpb,
    unsigned short* __restrict__ biasf, int jd, int tid, unsigned short* lds)
{
  int l = tid & 63, w = tid >> 6;
  int b = jd >> 9, r9 = jd & 511;
  int it = r9 >> 4, jt = r9 & 15;
  int i0 = it << 4, j0 = jt << 5;
  int kb = (l >> 4) << 3;
  int h = l & 15;
  short8 bf[4];
#pragma unroll
  for (int t = 0; t < 4; ++t){
#pragma unroll
    for (int j = 0; j < 8; ++j){
      int k = t * 32 + kb + j;
      float v = (h < 12) ? Wpb[k * 12 + h] : 0.f;
      bf[t][j] = (short)f2bf(v);
    }
  }
  float bb = (h < 12) ? bpb[h] : 0.f;

  for (int s = 0; s < 8; ++s){
    int tile = s * 4 + w;              // 0..31
    int iloc = tile >> 1, jh = tile & 1;
    long m = ((long)(b * 512 + i0 + iloc)) * 512 + j0 + jh * 16 + (l & 15);
    const float* pr = pair + m * 128 + kb;
    f32x4 acc = {0,0,0,0};
#pragma unroll
    for (int t = 0; t < 4; ++t){
      float4 x0 = *(const float4*)(pr + t * 32);
      float4 x1 = *(const float4*)(pr + t * 32 + 4);
      short8 a;
      a[0] = (short)f2bf(x0.x); a[1] = (short)f2bf(x0.y);
      a[2] = (short)f2bf(x0.z); a[3] = (short)f2bf(x0.w);
      a[4] = (short)f2bf(x1.x); a[5] = (short)f2bf(x1.y);
      a[6] = (short)f2bf(x1.z); a[7] = (short)f2bf(x1.w);
      acc = __builtin_amdgcn_mfma_f32_16x16x32_bf16(a, bf[t], acc, 0, 0, 0);
    }
    if (h < 12){
      int jloc = jh * 16 + ((l >> 4) << 2);
      unsigned short* dst = lds + (h * 17 + iloc) * 36 + jloc;
      uint2 wv; wv.x = pack2(acc[0] + bb, acc[1] + bb); wv.y = pack2(acc[2] + bb, acc[3] + bb);
      *(uint2*)dst = wv;
    }
  }
  __syncthreads();

  // cooperative coalesced write: 24 runs (h<12, f) x 64 uint2
  for (int e = tid; e < 12 * 2 * 64; e += 256){
    int run = e >> 6, idx = e & 63;
    int h2 = run >> 1, f = run & 1;
    int g2 = idx >> 4, q = idx & 15;
    const unsigned short* src = lds + (h2 * 17 + q) * 36 + f * 16 + g2 * 4;
    uint2 v = *(const uint2*)src;
    long base = ((((long)(b * 12 + h2) * 16 + jt) * 32 + it) * 2 + f) * 64 + idx;
    *(uint2*)(biasf + base * 4) = v;
  }
}

// ------------------------------------- k1: prep (weights/frag staging) + bias
__global__ __launch_bounds__(256) void k1_prep_bias(
    const float* __restrict__ single,
    const float* __restrict__ Wq, const float* __restrict__ Wk, const float* __restrict__ Wv,
    const float* __restrict__ Wqp, const float* __restrict__ Wkp, const float* __restrict__ Wvp,
    const float* __restrict__ bq, const float* __restrict__ bk, const float* __restrict__ bv,
    const float* __restrict__ bqp, const float* __restrict__ bkp, const float* __restrict__ bvp,
    const float* __restrict__ Wpo, const float* __restrict__ Wo,
    const float* __restrict__ pair, const float* __restrict__ Wpb, const float* __restrict__ bpb,
    unsigned short* __restrict__ sbf, unsigned short* __restrict__ wcat, float* __restrict__ bcat,
    unsigned short* __restrict__ wpof, unsigned short* __restrict__ wof,
    unsigned short* __restrict__ wppad, unsigned short* __restrict__ biasf,
    unsigned* __restrict__ cnt)
{
  __shared__ __align__(16) unsigned short blds[16 * 17 * 36];
  int bid = blockIdx.x, tid = threadIdx.x;
  if (bid >= 256){ bias_job16(pair, Wpb, bpb, biasf, bid - 256, tid, blds); return; }

  if (bid == 0 && tid < 64) cnt[tid] = 0;   // reset completion counters each call

  const int n0 = BN * Cc;
  const int n1 = 12 * CT1 * 512;
  const int n4 = NC1;
  const int n5 = 61440;
  const int n6 = 147456;
  const int n7 = BN * 16;
  const int total = n0 + n1 + n4 + n5 + n6 + n7;
  for (int i = bid * 256 + tid; i < total; i += 256 * 256){
    int e = i;
    if (e < n0){ sbf[e] = f2bf(single[e]); continue; }
    e -= n0;
    if (e < n1){
      int j8 = e & 7, l = (e >> 3) & 63, ctt = e >> 9;
      int ct = ctt % CT1, t = ctt / CT1;
      int k = t * 32 + ((l >> 4) << 3) + j8;
      int col = (ct << 4) + (l & 15);
      float v;
      if (col < 1152){
        const float* W = (col < 384) ? Wq : (col < 768 ? Wk : Wv);
        v = W[k * 384 + (col % 384)];
      } else {
        int c2 = col - 1152;
        const float* W = (c2 < 144) ? Wqp : (c2 < 288 ? Wkp : Wvp);
        v = W[k * 144 + (c2 % 144)];
      }
      wcat[e] = f2bf(v); continue;
    }
    e -= n1;
    if (e < n4){
      int col = e; float v;
      if (col < 1152){
        const float* bb = (col < 384) ? bq : (col < 768 ? bk : bv);
        v = bb[col % 384];
      } else {
        int c2 = col - 1152;
        const float* bb = (c2 < 144) ? bqp : (c2 < 288 ? bkp : bvp);
        v = bb[c2 % 144];
      }
      bcat[col] = v; continue;
    }
    e -= n4;
    if (e < n5){
      int j8 = e & 7, l = (e >> 3) & 63, ctt = e >> 9;
      int ct = ctt % 24, t = ctt / 24;
      int k = t * 32 + ((l >> 4) << 3) + j8;
      int col = (ct << 4) + (l & 15);
      wpof[e] = (k < 144) ? f2bf(Wpo[k * 384 + col]) : (unsigned short)0;
      continue;
    }
    e -= n5;
    if (e < n6){
      int j8 = e & 7, l = (e >> 3) & 63, ctt = e >> 9;
      int ct = ctt % 24, t = ctt / 24;
      int k = t * 32 + ((l >> 4) << 3) + j8;
      int col = (ct << 4) + (l & 15);
      wof[e] = f2bf(Wo[k * 384 + col]);
      continue;
    }
    e -= n6;
    { int row = e >> 4, c = e & 15; wppad[row * 160 + 144 + c] = 0; }
  }
}

// ----------------------------------------------- k2: proj GEMM + bias slice
__global__ __launch_bounds__(256) void k2_proj_bias(
    const unsigned short* __restrict__ sbf, const unsigned short* __restrict__ wcat,
    const float* __restrict__ bcat, float* __restrict__ proj,
    const float* __restrict__ pair, const float* __restrict__ Wpb, const float* __restrict__ bpb,
    unsigned short* __restrict__ biasf)
{
  __shared__ __align__(16) unsigned short blds[16 * 17 * 36];
  int bid = blockIdx.x, tid = threadIdx.x;
  if (bid >= 528){ bias_job16(pair, Wpb, bpb, biasf, 192 + (bid - 528), tid, blds); return; }

  int l = tid & 63, w = tid >> 6;
  int bx = bid & 15, by = bid >> 4;
  int m0 = bx * 64 + w * 16;
  const unsigned short* Ap = sbf + (long)(m0 + (l & 15)) * Cc + ((l >> 4) << 3);
  int ct0 = by * 3;
  f32x4 acc0 = {0,0,0,0}, acc1 = {0,0,0,0}, acc2 = {0,0,0,0};
  for (int t = 0; t < 12; ++t){
    short8 a = *(const short8*)(Ap + t * 32);
    const unsigned short* wp_ = wcat + ((long)(t * CT1 + ct0) * 64 + l) * 8;
    short8 b0 = *(const short8*)(wp_);
    short8 b1 = *(const short8*)(wp_ + 512);
    short8 b2 = *(const short8*)(wp_ + 1024);
    acc0 = __builtin_amdgcn_mfma_f32_16x16x32_bf16(a, b0, acc0, 0, 0, 0);
    acc1 = __builtin_amdgcn_mfma_f32_16x16x32_bf16(a, b1, acc1, 0, 0, 0);
    acc2 = __builtin_amdgcn_mfma_f32_16x16x32_bf16(a, b2, acc2, 0, 0, 0);
  }
  int rbase = m0 + ((l >> 4) << 2);
  int cb = by * 48 + (l & 15);
#pragma unroll
  for (int c = 0; c < 3; ++c){
    f32x4 ac = (c == 0) ? acc0 : (c == 1 ? acc1 : acc2);
    int col = cb + c * 16;
    float bb = bcat[col];
#pragma unroll
    for (int r = 0; r < 4; ++r)
      proj[(long)(rbase + r) * NC1 + col] = ac[r] + bb;
  }
}

// ----------------------------------------------- k3: pack + bias slice
__global__ __launch_bounds__(256) void k3_pack_bias(
    const float* __restrict__ proj, const float* __restrict__ rot,
    const float* __restrict__ trans, const float* __restrict__ mask,
    unsigned short* __restrict__ qf, unsigned short* __restrict__ kf,
    unsigned short* __restrict__ vf, float* __restrict__ q2h, float* __restrict__ k2h,
    const float* __restrict__ pair, const float* __restrict__ Wpb, const float* __restrict__ bpb,
    unsigned short* __restrict__ biasf)
{
  __shared__ __align__(16) unsigned char smem3[23168];
  int bid = blockIdx.x, tid = threadIdx.x;
  if (bid >= 384){
    bias_job16(pair, Wpb, bpb, biasf, 576 + (bid - 384), tid, (unsigned short*)smem3);
    return;
  }

  float* scal = (float*)smem3;
  float* praw = scal + 3072;
  float* pg   = praw + 1152;
  float* rots = pg + 1152;
  float* trs  = rots + 288;
  float* msk  = trs + 96;

  int jid = bid;
  int b = jid / 192, rem = jid % 192;
  int h = rem >> 4, rt = rem & 15;
  int j0 = rt * 32;
  int bn0 = b * 512 + j0;
  int bh = b * 12 + h;

  for (int idx = tid; idx < 3072; idx += 256){
    int a = idx >> 10, row = (idx >> 5) & 31, c = idx & 31;
    scal[idx] = proj[(long)(bn0 + row) * NC1 + a * 384 + h * 32 + c];
  }
  for (int idx = tid; idx < 1152; idx += 256){
    int a = idx / 384, rr = idx % 384, row = rr / 12, pe = rr % 12;
    praw[idx] = proj[(long)(bn0 + row) * NC1 + 1152 + a * 144 + h * 12 + pe];
  }
  for (int idx = tid; idx < 288; idx += 256) rots[idx] = rot[(long)bn0 * 9 + idx];
  for (int idx = tid; idx < 96; idx += 256)  trs[idx] = trans[(long)bn0 * 3 + idx];
  for (int idx = tid; idx < 32; idx += 256)  msk[idx] = mask[bn0 + idx];
  __syncthreads();

  for (int idx = tid; idx < 1152; idx += 256){
    int a = idx / 384, rr = idx % 384, row = rr / 12, pe = rr % 12;
    int p = pe / 3, ee = pe % 3;
    pg[idx] = praw[a * 384 + row * 12 + p * 3] * rots[row * 9 + ee]
            + praw[a * 384 + row * 12 + p * 3 + 1] * rots[row * 9 + 3 + ee]
            + praw[a * 384 + row * 12 + p * 3 + 2] * rots[row * 9 + 6 + ee] + trs[row * 3 + ee];
  }
  __syncthreads();

  for (int idx = tid; idx < 64; idx += 256){
    int a = idx >> 5, row = idx & 31;
    float s2 = 0.f;
#pragma unroll
    for (int pe = 0; pe < 12; ++pe){ float g = pg[a * 384 + row * 12 + pe]; s2 += g * g; }
    float mv = msk[row];
    float rres = -0.5f * SCALE * s2 + (mv != 0.f ? 0.f : -2e9f);
    (a ? k2h : q2h)[(long)bh * 512 + j0 + row] = rres;
  }

  for (int idx = tid; idx < 2048; idx += 256){
    int a = idx >> 10, r = idx & 1023;
    int jjp = r & 3, l = (r >> 2) & 63, ks = (r >> 8) & 1, sub = r >> 9;
    int row = sub * 16 + (l & 15);
    int kk = ks * 32 + ((l >> 4) << 3) + jjp * 2;
    int k1 = kk + 1;
    float v0 = (kk < 32) ? scal[a * 1024 + row * 32 + kk] : (kk < 44 ? pg[a * 384 + row * 12 + kk - 32] : 0.f);
    float v1 = (k1 < 32) ? scal[a * 1024 + row * 32 + k1] : (k1 < 44 ? pg[a * 384 + row * 12 + k1 - 32] : 0.f);
    if (a == 0){ v0 *= SCALE; v1 *= SCALE; }
    unsigned* dst = (unsigned*)(a ? kf : qf);
    dst[((((long)bh * 32 + rt * 2 + sub) * 2 + ks) * 64 + l) * 4 + jjp] = pack2(v0, v1);
  }

  for (int idx = tid; idx < 768; idx += 256){
    int jjp = idx & 3, l = (idx >> 2) & 63, cf = idx >> 8;
    int c = cf * 16 + (l & 15);
    int j = ((l >> 4) << 3) + jjp * 2;
    float v0 = (c < 32) ? scal[2048 + j * 32 + c]       : (c < 44 ? pg[768 + j * 12 + (c - 32)]       : 0.f);
    float v1 = (c < 32) ? scal[2048 + (j + 1) * 32 + c] : (c < 44 ? pg[768 + (j + 1) * 12 + (c - 32)] : 0.f);
    ((unsigned*)vf)[(((long)bh * 16 + rt) * 3 + cf) * 256 + l * 4 + jjp] = pack2(v0, v1);
  }
}

// ------------- flash MFMA attention (4 waves, 4 j-tiles) + fused per-rowgroup tail
__global__ __launch_bounds__(256) void attn2_kernel(
    const unsigned short* __restrict__ qf, const unsigned short* __restrict__ kf,
    const unsigned short* __restrict__ vf, const unsigned short* __restrict__ biasf,
    const float* __restrict__ q2h, const float* __restrict__ k2h,
    float* __restrict__ wsout, unsigned short* __restrict__ wpout,
    const unsigned short* __restrict__ wpof, const float* __restrict__ bpo,
    const unsigned short* __restrict__ wof, const float* __restrict__ bo,
    const float* __restrict__ single, const float* __restrict__ ln_g,
    const float* __restrict__ ln_b, float* __restrict__ out,
    unsigned* __restrict__ cnt)
{
  __shared__ unsigned short pls[4][16][40];
  __shared__ float oW[4][3][64][4];
  __shared__ float mW[4][16], lsW[4][16];
  __shared__ float fW[4][16], linvS[16];
  __shared__ unsigned short t1s[16][392];
  __shared__ float redS[4][16], redQ[4][16];
  __shared__ int lastflag;

  int l = threadIdx.x & 63, w = threadIdx.x >> 6;
  int qt = blockIdx.x, h = blockIdx.y, b = blockIdx.z;
  int bh = b * 12 + h;
  int g = l >> 4, q_ = l & 15;

  uint2 bpre[4][2];
#pragma unroll
  for (int ji = 0; ji < 4; ++ji){
    int jt = w * 4 + ji;
    const uint2* bp = (const uint2*)(biasf + ((((long)(bh * 16 + jt) * 32 + qt) * 2) * 64) * 4);
    bpre[ji][0] = bp[l];
    bpre[ji][1] = bp[64 + l];
  }

  const short8* qp = (const short8*)(qf + (((long)(bh * 32 + qt) * 2) * 64 + l) * 8);
  short8 qA = qp[0], qB = qp[64];
  float cq = q2h[(long)bh * 512 + qt * 16 + q_];

  float m = -1e30f, ls = 0.f;
  f32x4 o0 = {0,0,0,0}, o1 = {0,0,0,0}, o2 = {0,0,0,0};
  const f32x4 z4 = {0,0,0,0};

#pragma unroll
  for (int ji = 0; ji < 4; ++ji){
    int jt = w * 4 + ji;
    const short8* kp = (const short8*)(kf + (((long)(bh * 32 + jt * 2) * 2) * 64 + l) * 8);
    short8 k00 = kp[0], k01 = kp[64], k10 = kp[128], k11 = kp[192];
    f32x4 s0 = __builtin_amdgcn_mfma_f32_16x16x32_bf16(k00, qA, z4, 0, 0, 0);
    s0 = __builtin_amdgcn_mfma_f32_16x16x32_bf16(k01, qB, s0, 0, 0, 0);
    f32x4 s1 = __builtin_amdgcn_mfma_f32_16x16x32_bf16(k10, qA, z4, 0, 0, 0);
    s1 = __builtin_amdgcn_mfma_f32_16x16x32_bf16(k11, qB, s1, 0, 0, 0);

    uint2 bb0 = bpre[ji][0], bb1 = bpre[ji][1];
    const float4* k2p = (const float4*)(k2h + (long)bh * 512 + jt * 32);
    float4 ck0 = k2p[g], ck1 = k2p[4 + g];

    s0[0] += bf_lo(bb0.x) + cq + ck0.x;
    s0[1] += bf_hi(bb0.x) + cq + ck0.y;
    s0[2] += bf_lo(bb0.y) + cq + ck0.z;
    s0[3] += bf_hi(bb0.y) + cq + ck0.w;
    s1[0] += bf_lo(bb1.x) + cq + ck1.x;
    s1[1] += bf_hi(bb1.x) + cq + ck1.y;
    s1[2] += bf_lo(bb1.y) + cq + ck1.z;
    s1[3] += bf_hi(bb1.y) + cq + ck1.w;

    float tm = fmaxf(fmaxf(fmaxf(s0[0], s0[1]), fmaxf(s0[2], s0[3])),
                     fmaxf(fmaxf(s1[0], s1[1]), fmaxf(s1[2], s1[3])));
    tm = fmaxf(tm, __shfl_xor(tm, 16));
    tm = fmaxf(tm, __shfl_xor(tm, 32));
    float mn = fmaxf(m, tm);
    float alpha = __expf(m - mn);
    f32x4 p0, p1;
    float ts = 0.f;
#pragma unroll
    for (int r = 0; r < 4; ++r){ p0[r] = __expf(s0[r] - mn); ts += p0[r]; }
#pragma unroll
    for (int r = 0; r < 4; ++r){ p1[r] = __expf(s1[r] - mn); ts += p1[r]; }
    ts += __shfl_xor(ts, 16);
    ts += __shfl_xor(ts, 32);
    ls = ls * alpha + ts; m = mn;

    f32x4 av;
#pragma unroll
    for (int r = 0; r < 4; ++r) av[r] = __shfl(alpha, g * 4 + r);
#pragma unroll
    for (int r = 0; r < 4; ++r){ o0[r] *= av[r]; o1[r] *= av[r]; o2[r] *= av[r]; }

    uint2 w0; w0.x = pack2(p0[0], p0[1]); w0.y = pack2(p0[2], p0[3]);
    uint2 w1; w1.x = pack2(p1[0], p1[1]); w1.y = pack2(p1[2], p1[3]);
    *(uint2*)&pls[w][q_][g * 4]      = w0;
    *(uint2*)&pls[w][q_][16 + g * 4] = w1;
    short8 pa = *(const short8*)&pls[w][q_][g * 8];

    const short8* vp = (const short8*)(vf + (((long)(bh * 16 + jt) * 3) * 64 + l) * 8);
    short8 v0 = vp[0], v1 = vp[64], v2 = vp[128];
    o0 = __builtin_amdgcn_mfma_f32_16x16x32_bf16(pa, v0, o0, 0, 0, 0);
    o1 = __builtin_amdgcn_mfma_f32_16x16x32_bf16(pa, v1, o1, 0, 0, 0);
    o2 = __builtin_amdgcn_mfma_f32_16x16x32_bf16(pa, v2, o2, 0, 0, 0);
  }

  if (g == 0){ mW[w][q_] = m; lsW[w][q_] = ls; }
  *(f32x4*)&oW[w][0][l][0] = o0;
  *(f32x4*)&oW[w][1][l][0] = o1;
  *(f32x4*)&oW[w][2][l][0] = o2;
  __syncthreads();

  if (w == 0){
    float M = fmaxf(fmaxf(mW[0][q_], mW[1][q_]), fmaxf(mW[2][q_], mW[3][q_]));
    float f = __expf(mW[g][q_] - M);
    fW[g][q_] = f;
    float lf = lsW[g][q_] * f;
    lf += __shfl_xor(lf, 16);
    lf += __shfl_xor(lf, 32);
    if (g == 0) linvS[q_] = 1.f / lf;
  }
  __syncthreads();

  if (w < 3){
    float fr[4][4], li[4];
#pragma unroll
    for (int r = 0; r < 4; ++r){
      int q = g * 4 + r;
      li[r] = linvS[q];
#pragma unroll
      for (int vw = 0; vw < 4; ++vw) fr[vw][r] = fW[vw][q];
    }
    f32x4 sum = {0,0,0,0};
#pragma unroll
    for (int vw = 0; vw < 4; ++vw){
      f32x4 ov = *(const f32x4*)&oW[vw][w][l][0];
#pragma unroll
      for (int r = 0; r < 4; ++r) sum[r] += ov[r] * fr[vw][r];
    }
#pragma unroll
    for (int r = 0; r < 4; ++r){
      long bn = (long)b * 512 + qt * 16 + g * 4 + r;
      float val = sum[r] * li[r];
      if (w == 0)      wsout[bn * 384 + h * 32 + q_] = val;
      else if (w == 1) wsout[bn * 384 + h * 32 + 16 + q_] = val;
      else if (q_ < 12) wpout[bn * 160 + h * 12 + q_] = f2bf(val);
    }
  }

  // ---- completion counting: 12th block for this (b,qt) runs the tail
  __threadfence();
  __syncthreads();
  if (threadIdx.x == 0){
    unsigned old = atomicAdd(&cnt[b * 32 + qt], 1u);
    lastflag = (old == 11u);
  }
  __syncthreads();
  if (!lastflag) return;
  __threadfence();

  // ---- fused tail for rows [m0t, m0t+16)
  int m0t = b * 512 + qt * 16;
  int rb = (l >> 4) << 2;
  int arow = m0t + (l & 15);
  {
    short8 awp[5];
    const unsigned short* Ap = wpout + (long)arow * 160 + ((l >> 4) << 3);
#pragma unroll
    for (int t = 0; t < 5; ++t) awp[t] = *(const short8*)(Ap + t * 32);
#pragma unroll
    for (int c6 = 0; c6 < 6; ++c6){
      int ct = w * 6 + c6;
      f32x4 acc = {0,0,0,0};
#pragma unroll
      for (int t = 0; t < 5; ++t){
        short8 bfr = *(const short8*)(wpof + ((long)(t * 24 + ct) * 64 + l) * 8);
        acc = __builtin_amdgcn_mfma_f32_16x16x32_bf16(awp[t], bfr, acc, 0, 0, 0);
      }
      int col = ct * 16 + (l & 15);
      float bb = bpo[col];
#pragma unroll
      for (int r = 0; r < 4; ++r){
        float v = acc[r] + bb + wsout[(long)(m0t + rb + r) * 384 + col];
        t1s[rb + r][col] = f2bf(v);
      }
    }
  }
  __syncthreads();

  short8 a2[12];
  {
    int lr = l & 15;
#pragma unroll
    for (int t = 0; t < 12; ++t)
      a2[t] = *(const short8*)&t1s[lr][t * 32 + ((l >> 4) << 3)];
  }
  f32x4 xa[6];
  float s1a[4] = {0,0,0,0}, s2a[4] = {0,0,0,0};
#pragma unroll
  for (int c6 = 0; c6 < 6; ++c6){
    int ct = w * 6 + c6;
    f32x4 acc = {0,0,0,0};
#pragma unroll
    for (int t = 0; t < 12; ++t){
      short8 bfr = *(const short8*)(wof + ((long)(t * 24 + ct) * 64 + l) * 8);
      acc = __builtin_amdgcn_mfma_f32_16x16x32_bf16(a2[t], bfr, acc, 0, 0, 0);
    }
    int col = ct * 16 + (l & 15);
    float bb = bo[col];
#pragma unroll
    for (int r = 0; r < 4; ++r){
      float v = acc[r] + bb + single[(long)(m0t + rb + r) * 384 + col];
      acc[r] = v; s1a[r] += v; s2a[r] += v * v;
    }
    xa[c6] = acc;
  }
#pragma unroll
  for (int off = 1; off < 16; off <<= 1){
#pragma unroll
    for (int r = 0; r < 4; ++r){
      s1a[r] += __shfl_xor(s1a[r], off);
      s2a[r] += __shfl_xor(s2a[r], off);
    }
  }
  if ((l & 15) == 0){
#pragma unroll
    for (int r = 0; r < 4; ++r){ redS[w][rb + r] = s1a[r]; redQ[w][rb + r] = s2a[r]; }
  }
  __syncthreads();
  float mu[4], inv[4];
#pragma unroll
  for (int r = 0; r < 4; ++r){
    float ts = redS[0][rb + r] + redS[1][rb + r] + redS[2][rb + r] + redS[3][rb + r];
    float tq = redQ[0][rb + r] + redQ[1][rb + r] + redQ[2][rb + r] + redQ[3][rb + r];
    mu[r] = ts * (1.f / 384.f);
    float var = tq * (1.f / 384.f) - mu[r] * mu[r];
    inv[r] = rsqrtf(var + 1e-5f);
  }
#pragma unroll
  for (int c6 = 0; c6 < 6; ++c6){
    int ct = w * 6 + c6;
    int col = ct * 16 + (l & 15);
    float gg = ln_g[col], bt = ln_b[col];
#pragma unroll
    for (int r = 0; r < 4; ++r)
      out[(long)(m0t + rb + r) * 384 + col] = (xa[c6][r] - mu[r]) * inv[r] * gg + bt;
  }
}

// -------------------------------------------------------------------- launcher
extern "C" void kernel_launch(void* const* d_in, const int* in_sizes, int n_in,
                              void* d_out, int out_size, void* d_ws, size_t ws_size,
                              hipStream_t stream)
{
  const float* single = (const float*)d_in[0];
  const float* pair   = (const float*)d_in[1];
  const float* rot    = (const float*)d_in[2];
  const float* trans  = (const float*)d_in[3];
  const float* mask   = (const float*)d_in[4];
  const float* Wq  = (const float*)d_in[5];  const float* bq  = (const float*)d_in[6];
  const float* Wk  = (const float*)d_in[7];  const float* bk  = (const float*)d_in[8];
  const float* Wv  = (const float*)d_in[9];  const float* bv  = (const float*)d_in[10];
  const float* Wpb = (const float*)d_in[11]; const float* bpb = (const float*)d_in[12];
  const float* Wqp = (const float*)d_in[13]; const float* bqp = (const float*)d_in[14];
  const float* Wkp = (const float*)d_in[15]; const float* bkp = (const float*)d_in[16];
  const float* Wvp = (const float*)d_in[17]; const float* bvp = (const float*)d_in[18];
  const float* Wo  = (const float*)d_in[19]; const float* bo  = (const float*)d_in[20];
  const float* Wpo = (const float*)d_in[21]; const float* bpo = (const float*)d_in[22];
  const float* ln_g = (const float*)d_in[23]; const float* ln_b = (const float*)d_in[24];

  char* wsb = (char*)d_ws;
  size_t off = 0;
  auto alloc = [&](size_t bytes) -> void* {
    void* p = wsb + off; off += (bytes + 255) & ~(size_t)255; return p;
  };
  unsigned short* sbf  = (unsigned short*)alloc((size_t)BN * Cc * 2);
  unsigned short* wcat = (unsigned short*)alloc((size_t)12 * CT1 * 512 * 2);
  unsigned short* wpof = (unsigned short*)alloc((size_t)5 * 24 * 512 * 2);
  unsigned short* wof  = (unsigned short*)alloc((size_t)12 * 24 * 512 * 2);
  float* bcat  = (float*)alloc(NC1 * 4);
  float* proj  = (float*)alloc((size_t)BN * NC1 * 4);
  unsigned short* biasf = (unsigned short*)alloc((size_t)Bb * Hh * Nn * Nn * 2);
  unsigned short* qfragb = (unsigned short*)alloc((size_t)786432 * 2);
  unsigned short* kfragb = (unsigned short*)alloc((size_t)786432 * 2);
  unsigned short* vfragb = (unsigned short*)alloc((size_t)589824 * 2);
  float* q2hb  = (float*)alloc((size_t)12288 * 4);
  float* k2hb  = (float*)alloc((size_t)12288 * 4);
  float* wso   = (float*)alloc((size_t)BN * 384 * 4);
  unsigned short* wpbuf = (unsigned short*)alloc((size_t)BN * 160 * 2);
  unsigned* cnt = (unsigned*)alloc(64 * 4);
  if (off > ws_size) return;

  // bias tile jobs: 1024 total; k1: [0,192), k2: [192,576), k3: [576,1024)
  k1_prep_bias<<<256 + 192, 256, 0, stream>>>(
      single, Wq, Wk, Wv, Wqp, Wkp, Wvp, bq, bk, bv, bqp, bkp, bvp, Wpo, Wo,
      pair, Wpb, bpb, sbf, wcat, bcat, wpof, wof, wpbuf, biasf, cnt);
  k2_proj_bias<<<528 + 384, 256, 0, stream>>>(
      sbf, wcat, bcat, proj, pair, Wpb, bpb, biasf);
  k3_pack_bias<<<384 + 448, 256, 0, stream>>>(
      proj, rot, trans, mask, qfragb, kfragb, vfragb, q2hb, k2hb,
      pair, Wpb, bpb, biasf);
  attn2_kernel<<<dim3(32, 12, 2), 256, 0, stream>>>(
      qfragb, kfragb, vfragb, biasf, q2hb, k2hb, wso, wpbuf,
      wpof, bpo, wof, bo, single, ln_g, ln_b, (float*)d_out, cnt);
}

// Round 15
// 92.949 us; speedup vs baseline: 1.8213x; 1.8213x over previous
//
#include <hip/hip_runtime.h>
#include <hip/hip_bf16.h>

// Problem constants
#define Bb   2
#define Nn   512
#define Cc   384
#define Hh   12
#define BN   1024          // B*N
#define NC1  1584          // 3*384 + 3*144 concatenated proj cols
#define CT1  99            // 1584/16 col-tiles
#define SCALE 0.17677669529663687f   // 32^-0.5

typedef __attribute__((ext_vector_type(8))) short short8;
typedef __attribute__((ext_vector_type(4))) float f32x4;

__device__ __forceinline__ unsigned short f2bf(float f){
  union { float f; unsigned u; } v; v.f = f;
  unsigned u = v.u;
  unsigned r = u + 0x7fffu + ((u >> 16) & 1u);
  return (unsigned short)(r >> 16);
}
__device__ __forceinline__ float bf_lo(unsigned u){ union{unsigned u; float f;} v; v.u = u << 16; return v.f; }
__device__ __forceinline__ float bf_hi(unsigned u){ union{unsigned u; float f;} v; v.u = u & 0xffff0000u; return v.f; }
__device__ __forceinline__ unsigned pack2(float a, float b){
  return (unsigned)f2bf(a) | ((unsigned)f2bf(b) << 16);
}

// --------------------- bias tile job: 16i x 32j, LDS-staged coalesced writes
// lds: unsigned short [16][17][36]  (19584 B)
__device__ __forceinline__ void bias_job16(const float* __restrict__ pair,
    const float* __restrict__ Wpb, const float* __restrict__ bpb,
    unsigned short* __restrict__ biasf, int jd, int tid, unsigned short* lds)
{
  int l = tid & 63, w = tid >> 6;
  int b = jd >> 9, r9 = jd & 511;
  int it = r9 >> 4, jt = r9 & 15;
  int i0 = it << 4, j0 = jt << 5;
  int kb = (l >> 4) << 3;
  int h = l & 15;
  short8 bf[4];
#pragma unroll
  for (int t = 0; t < 4; ++t){
#pragma unroll
    for (int j = 0; j < 8; ++j){
      int k = t * 32 + kb + j;
      float v = (h < 12) ? Wpb[k * 12 + h] : 0.f;
      bf[t][j] = (short)f2bf(v);
    }
  }
  float bb = (h < 12) ? bpb[h] : 0.f;

  for (int s = 0; s < 8; ++s){
    int tile = s * 4 + w;              // 0..31
    int iloc = tile >> 1, jh = tile & 1;
    long m = ((long)(b * 512 + i0 + iloc)) * 512 + j0 + jh * 16 + (l & 15);
    const float* pr = pair + m * 128 + kb;
    f32x4 acc = {0,0,0,0};
#pragma unroll
    for (int t = 0; t < 4; ++t){
      float4 x0 = *(const float4*)(pr + t * 32);
      float4 x1 = *(const float4*)(pr + t * 32 + 4);
      short8 a;
      a[0] = (short)f2bf(x0.x); a[1] = (short)f2bf(x0.y);
      a[2] = (short)f2bf(x0.z); a[3] = (short)f2bf(x0.w);
      a[4] = (short)f2bf(x1.x); a[5] = (short)f2bf(x1.y);
      a[6] = (short)f2bf(x1.z); a[7] = (short)f2bf(x1.w);
      acc = __builtin_amdgcn_mfma_f32_16x16x32_bf16(a, bf[t], acc, 0, 0, 0);
    }
    if (h < 12){
      int jloc = jh * 16 + ((l >> 4) << 2);
      unsigned short* dst = lds + (h * 17 + iloc) * 36 + jloc;
      uint2 wv; wv.x = pack2(acc[0] + bb, acc[1] + bb); wv.y = pack2(acc[2] + bb, acc[3] + bb);
      *(uint2*)dst = wv;
    }
  }
  __syncthreads();

  // cooperative coalesced write: 24 runs (h<12, f) x 64 uint2
  for (int e = tid; e < 12 * 2 * 64; e += 256){
    int run = e >> 6, idx = e & 63;
    int h2 = run >> 1, f = run & 1;
    int g2 = idx >> 4, q = idx & 15;
    const unsigned short* src = lds + (h2 * 17 + q) * 36 + f * 16 + g2 * 4;
    uint2 v = *(const uint2*)src;
    long base = ((((long)(b * 12 + h2) * 16 + jt) * 32 + it) * 2 + f) * 64 + idx;
    *(uint2*)(biasf + base * 4) = v;
  }
}

// ------------------------------------- k1: prep (weights/frag staging) + bias
__global__ __launch_bounds__(256) void k1_prep_bias(
    const float* __restrict__ single,
    const float* __restrict__ Wq, const float* __restrict__ Wk, const float* __restrict__ Wv,
    const float* __restrict__ Wqp, const float* __restrict__ Wkp, const float* __restrict__ Wvp,
    const float* __restrict__ bq, const float* __restrict__ bk, const float* __restrict__ bv,
    const float* __restrict__ bqp, const float* __restrict__ bkp, const float* __restrict__ bvp,
    const float* __restrict__ Wpo, const float* __restrict__ Wo,
    const float* __restrict__ pair, const float* __restrict__ Wpb, const float* __restrict__ bpb,
    unsigned short* __restrict__ sbf, unsigned short* __restrict__ wcat, float* __restrict__ bcat,
    unsigned short* __restrict__ wpof, unsigned short* __restrict__ wof,
    unsigned short* __restrict__ wppad, unsigned short* __restrict__ biasf)
{
  __shared__ __align__(16) unsigned short blds[16 * 17 * 36];
  int bid = blockIdx.x, tid = threadIdx.x;
  if (bid >= 256){ bias_job16(pair, Wpb, bpb, biasf, bid - 256, tid, blds); return; }

  const int n0 = BN * Cc;
  const int n1 = 12 * CT1 * 512;
  const int n4 = NC1;
  const int n5 = 61440;
  const int n6 = 147456;
  const int n7 = BN * 16;
  const int total = n0 + n1 + n4 + n5 + n6 + n7;
  for (int i = bid * 256 + tid; i < total; i += 256 * 256){
    int e = i;
    if (e < n0){ sbf[e] = f2bf(single[e]); continue; }
    e -= n0;
    if (e < n1){
      int j8 = e & 7, l = (e >> 3) & 63, ctt = e >> 9;
      int ct = ctt % CT1, t = ctt / CT1;
      int k = t * 32 + ((l >> 4) << 3) + j8;
      int col = (ct << 4) + (l & 15);
      float v;
      if (col < 1152){
        const float* W = (col < 384) ? Wq : (col < 768 ? Wk : Wv);
        v = W[k * 384 + (col % 384)];
      } else {
        int c2 = col - 1152;
        const float* W = (c2 < 144) ? Wqp : (c2 < 288 ? Wkp : Wvp);
        v = W[k * 144 + (c2 % 144)];
      }
      wcat[e] = f2bf(v); continue;
    }
    e -= n1;
    if (e < n4){
      int col = e; float v;
      if (col < 1152){
        const float* bb = (col < 384) ? bq : (col < 768 ? bk : bv);
        v = bb[col % 384];
      } else {
        int c2 = col - 1152;
        const float* bb = (c2 < 144) ? bqp : (c2 < 288 ? bkp : bvp);
        v = bb[c2 % 144];
      }
      bcat[col] = v; continue;
    }
    e -= n4;
    if (e < n5){
      int j8 = e & 7, l = (e >> 3) & 63, ctt = e >> 9;
      int ct = ctt % 24, t = ctt / 24;
      int k = t * 32 + ((l >> 4) << 3) + j8;
      int col = (ct << 4) + (l & 15);
      wpof[e] = (k < 144) ? f2bf(Wpo[k * 384 + col]) : (unsigned short)0;
      continue;
    }
    e -= n5;
    if (e < n6){
      int j8 = e & 7, l = (e >> 3) & 63, ctt = e >> 9;
      int ct = ctt % 24, t = ctt / 24;
      int k = t * 32 + ((l >> 4) << 3) + j8;
      int col = (ct << 4) + (l & 15);
      wof[e] = f2bf(Wo[k * 384 + col]);
      continue;
    }
    e -= n6;
    { int row = e >> 4, c = e & 15; wppad[row * 160 + 144 + c] = 0; }
  }
}

// ----------------------------------------------- k2: proj GEMM + bias slice
__global__ __launch_bounds__(256) void k2_proj_bias(
    const unsigned short* __restrict__ sbf, const unsigned short* __restrict__ wcat,
    const float* __restrict__ bcat, float* __restrict__ proj,
    const float* __restrict__ pair, const float* __restrict__ Wpb, const float* __restrict__ bpb,
    unsigned short* __restrict__ biasf)
{
  __shared__ __align__(16) unsigned short blds[16 * 17 * 36];
  int bid = blockIdx.x, tid = threadIdx.x;
  if (bid >= 528){ bias_job16(pair, Wpb, bpb, biasf, 192 + (bid - 528), tid, blds); return; }

  int l = tid & 63, w = tid >> 6;
  int bx = bid & 15, by = bid >> 4;
  int m0 = bx * 64 + w * 16;
  const unsigned short* Ap = sbf + (long)(m0 + (l & 15)) * Cc + ((l >> 4) << 3);
  int ct0 = by * 3;
  f32x4 acc0 = {0,0,0,0}, acc1 = {0,0,0,0}, acc2 = {0,0,0,0};
  for (int t = 0; t < 12; ++t){
    short8 a = *(const short8*)(Ap + t * 32);
    const unsigned short* wp_ = wcat + ((long)(t * CT1 + ct0) * 64 + l) * 8;
    short8 b0 = *(const short8*)(wp_);
    short8 b1 = *(const short8*)(wp_ + 512);
    short8 b2 = *(const short8*)(wp_ + 1024);
    acc0 = __builtin_amdgcn_mfma_f32_16x16x32_bf16(a, b0, acc0, 0, 0, 0);
    acc1 = __builtin_amdgcn_mfma_f32_16x16x32_bf16(a, b1, acc1, 0, 0, 0);
    acc2 = __builtin_amdgcn_mfma_f32_16x16x32_bf16(a, b2, acc2, 0, 0, 0);
  }
  int rbase = m0 + ((l >> 4) << 2);
  int cb = by * 48 + (l & 15);
#pragma unroll
  for (int c = 0; c < 3; ++c){
    f32x4 ac = (c == 0) ? acc0 : (c == 1 ? acc1 : acc2);
    int col = cb + c * 16;
    float bb = bcat[col];
#pragma unroll
    for (int r = 0; r < 4; ++r)
      proj[(long)(rbase + r) * NC1 + col] = ac[r] + bb;
  }
}

// ----------------------------------------------- k3: pack + bias slice
__global__ __launch_bounds__(256) void k3_pack_bias(
    const float* __restrict__ proj, const float* __restrict__ rot,
    const float* __restrict__ trans, const float* __restrict__ mask,
    unsigned short* __restrict__ qf, unsigned short* __restrict__ kf,
    unsigned short* __restrict__ vf, float* __restrict__ q2h, float* __restrict__ k2h,
    const float* __restrict__ pair, const float* __restrict__ Wpb, const float* __restrict__ bpb,
    unsigned short* __restrict__ biasf)
{
  __shared__ __align__(16) unsigned char smem3[23168];
  int bid = blockIdx.x, tid = threadIdx.x;
  if (bid >= 384){
    bias_job16(pair, Wpb, bpb, biasf, 576 + (bid - 384), tid, (unsigned short*)smem3);
    return;
  }

  float* scal = (float*)smem3;
  float* praw = scal + 3072;
  float* pg   = praw + 1152;
  float* rots = pg + 1152;
  float* trs  = rots + 288;
  float* msk  = trs + 96;

  int jid = bid;
  int b = jid / 192, rem = jid % 192;
  int h = rem >> 4, rt = rem & 15;
  int j0 = rt * 32;
  int bn0 = b * 512 + j0;
  int bh = b * 12 + h;

  for (int idx = tid; idx < 3072; idx += 256){
    int a = idx >> 10, row = (idx >> 5) & 31, c = idx & 31;
    scal[idx] = proj[(long)(bn0 + row) * NC1 + a * 384 + h * 32 + c];
  }
  for (int idx = tid; idx < 1152; idx += 256){
    int a = idx / 384, rr = idx % 384, row = rr / 12, pe = rr % 12;
    praw[idx] = proj[(long)(bn0 + row) * NC1 + 1152 + a * 144 + h * 12 + pe];
  }
  for (int idx = tid; idx < 288; idx += 256) rots[idx] = rot[(long)bn0 * 9 + idx];
  for (int idx = tid; idx < 96; idx += 256)  trs[idx] = trans[(long)bn0 * 3 + idx];
  for (int idx = tid; idx < 32; idx += 256)  msk[idx] = mask[bn0 + idx];
  __syncthreads();

  for (int idx = tid; idx < 1152; idx += 256){
    int a = idx / 384, rr = idx % 384, row = rr / 12, pe = rr % 12;
    int p = pe / 3, ee = pe % 3;
    pg[idx] = praw[a * 384 + row * 12 + p * 3] * rots[row * 9 + ee]
            + praw[a * 384 + row * 12 + p * 3 + 1] * rots[row * 9 + 3 + ee]
            + praw[a * 384 + row * 12 + p * 3 + 2] * rots[row * 9 + 6 + ee] + trs[row * 3 + ee];
  }
  __syncthreads();

  for (int idx = tid; idx < 64; idx += 256){
    int a = idx >> 5, row = idx & 31;
    float s2 = 0.f;
#pragma unroll
    for (int pe = 0; pe < 12; ++pe){ float g = pg[a * 384 + row * 12 + pe]; s2 += g * g; }
    float mv = msk[row];
    float rres = -0.5f * SCALE * s2 + (mv != 0.f ? 0.f : -2e9f);
    (a ? k2h : q2h)[(long)bh * 512 + j0 + row] = rres;
  }

  for (int idx = tid; idx < 2048; idx += 256){
    int a = idx >> 10, r = idx & 1023;
    int jjp = r & 3, l = (r >> 2) & 63, ks = (r >> 8) & 1, sub = r >> 9;
    int row = sub * 16 + (l & 15);
    int kk = ks * 32 + ((l >> 4) << 3) + jjp * 2;
    int k1 = kk + 1;
    float v0 = (kk < 32) ? scal[a * 1024 + row * 32 + kk] : (kk < 44 ? pg[a * 384 + row * 12 + kk - 32] : 0.f);
    float v1 = (k1 < 32) ? scal[a * 1024 + row * 32 + k1] : (k1 < 44 ? pg[a * 384 + row * 12 + k1 - 32] : 0.f);
    if (a == 0){ v0 *= SCALE; v1 *= SCALE; }
    unsigned* dst = (unsigned*)(a ? kf : qf);
    dst[((((long)bh * 32 + rt * 2 + sub) * 2 + ks) * 64 + l) * 4 + jjp] = pack2(v0, v1);
  }

  for (int idx = tid; idx < 768; idx += 256){
    int jjp = idx & 3, l = (idx >> 2) & 63, cf = idx >> 8;
    int c = cf * 16 + (l & 15);
    int j = ((l >> 4) << 3) + jjp * 2;
    float v0 = (c < 32) ? scal[2048 + j * 32 + c]       : (c < 44 ? pg[768 + j * 12 + (c - 32)]       : 0.f);
    float v1 = (c < 32) ? scal[2048 + (j + 1) * 32 + c] : (c < 44 ? pg[768 + (j + 1) * 12 + (c - 32)] : 0.f);
    ((unsigned*)vf)[(((long)bh * 16 + rt) * 3 + cf) * 256 + l * 4 + jjp] = pack2(v0, v1);
  }
}

// ------------- flash MFMA attention: 4 waves/block, 4 j-tiles each + LDS merge
__global__ __launch_bounds__(256) void attn2_kernel(
    const unsigned short* __restrict__ qf, const unsigned short* __restrict__ kf,
    const unsigned short* __restrict__ vf, const unsigned short* __restrict__ biasf,
    const float* __restrict__ q2h, const float* __restrict__ k2h,
    float* __restrict__ wsout, unsigned short* __restrict__ wpout)
{
  __shared__ unsigned short pls[4][16][40];
  __shared__ float oW[4][3][64][4];
  __shared__ float mW[4][16], lsW[4][16];
  __shared__ float fW[4][16], linvS[16];

  int l = threadIdx.x & 63, w = threadIdx.x >> 6;
  int qt = blockIdx.x, h = blockIdx.y, b = blockIdx.z;
  int bh = b * 12 + h;
  int g = l >> 4, q_ = l & 15;

  uint2 bpre[4][2];
#pragma unroll
  for (int ji = 0; ji < 4; ++ji){
    int jt = w * 4 + ji;
    const uint2* bp = (const uint2*)(biasf + ((((long)(bh * 16 + jt) * 32 + qt) * 2) * 64) * 4);
    bpre[ji][0] = bp[l];
    bpre[ji][1] = bp[64 + l];
  }

  const short8* qp = (const short8*)(qf + (((long)(bh * 32 + qt) * 2) * 64 + l) * 8);
  short8 qA = qp[0], qB = qp[64];
  float cq = q2h[(long)bh * 512 + qt * 16 + q_];

  float m = -1e30f, ls = 0.f;
  f32x4 o0 = {0,0,0,0}, o1 = {0,0,0,0}, o2 = {0,0,0,0};
  const f32x4 z4 = {0,0,0,0};

#pragma unroll
  for (int ji = 0; ji < 4; ++ji){
    int jt = w * 4 + ji;
    const short8* kp = (const short8*)(kf + (((long)(bh * 32 + jt * 2) * 2) * 64 + l) * 8);
    short8 k00 = kp[0], k01 = kp[64], k10 = kp[128], k11 = kp[192];
    f32x4 s0 = __builtin_amdgcn_mfma_f32_16x16x32_bf16(k00, qA, z4, 0, 0, 0);
    s0 = __builtin_amdgcn_mfma_f32_16x16x32_bf16(k01, qB, s0, 0, 0, 0);
    f32x4 s1 = __builtin_amdgcn_mfma_f32_16x16x32_bf16(k10, qA, z4, 0, 0, 0);
    s1 = __builtin_amdgcn_mfma_f32_16x16x32_bf16(k11, qB, s1, 0, 0, 0);

    uint2 bb0 = bpre[ji][0], bb1 = bpre[ji][1];
    const float4* k2p = (const float4*)(k2h + (long)bh * 512 + jt * 32);
    float4 ck0 = k2p[g], ck1 = k2p[4 + g];

    s0[0] += bf_lo(bb0.x) + cq + ck0.x;
    s0[1] += bf_hi(bb0.x) + cq + ck0.y;
    s0[2] += bf_lo(bb0.y) + cq + ck0.z;
    s0[3] += bf_hi(bb0.y) + cq + ck0.w;
    s1[0] += bf_lo(bb1.x) + cq + ck1.x;
    s1[1] += bf_hi(bb1.x) + cq + ck1.y;
    s1[2] += bf_lo(bb1.y) + cq + ck1.z;
    s1[3] += bf_hi(bb1.y) + cq + ck1.w;

    float tm = fmaxf(fmaxf(fmaxf(s0[0], s0[1]), fmaxf(s0[2], s0[3])),
                     fmaxf(fmaxf(s1[0], s1[1]), fmaxf(s1[2], s1[3])));
    tm = fmaxf(tm, __shfl_xor(tm, 16));
    tm = fmaxf(tm, __shfl_xor(tm, 32));
    float mn = fmaxf(m, tm);
    float alpha = __expf(m - mn);
    f32x4 p0, p1;
    float ts = 0.f;
#pragma unroll
    for (int r = 0; r < 4; ++r){ p0[r] = __expf(s0[r] - mn); ts += p0[r]; }
#pragma unroll
    for (int r = 0; r < 4; ++r){ p1[r] = __expf(s1[r] - mn); ts += p1[r]; }
    ts += __shfl_xor(ts, 16);
    ts += __shfl_xor(ts, 32);
    ls = ls * alpha + ts; m = mn;

    f32x4 av;
#pragma unroll
    for (int r = 0; r < 4; ++r) av[r] = __shfl(alpha, g * 4 + r);
#pragma unroll
    for (int r = 0; r < 4; ++r){ o0[r] *= av[r]; o1[r] *= av[r]; o2[r] *= av[r]; }

    uint2 w0; w0.x = pack2(p0[0], p0[1]); w0.y = pack2(p0[2], p0[3]);
    uint2 w1; w1.x = pack2(p1[0], p1[1]); w1.y = pack2(p1[2], p1[3]);
    *(uint2*)&pls[w][q_][g * 4]      = w0;
    *(uint2*)&pls[w][q_][16 + g * 4] = w1;
    short8 pa = *(const short8*)&pls[w][q_][g * 8];

    const short8* vp = (const short8*)(vf + (((long)(bh * 16 + jt) * 3) * 64 + l) * 8);
    short8 v0 = vp[0], v1 = vp[64], v2 = vp[128];
    o0 = __builtin_amdgcn_mfma_f32_16x16x32_bf16(pa, v0, o0, 0, 0, 0);
    o1 = __builtin_amdgcn_mfma_f32_16x16x32_bf16(pa, v1, o1, 0, 0, 0);
    o2 = __builtin_amdgcn_mfma_f32_16x16x32_bf16(pa, v2, o2, 0, 0, 0);
  }

  if (g == 0){ mW[w][q_] = m; lsW[w][q_] = ls; }
  *(f32x4*)&oW[w][0][l][0] = o0;
  *(f32x4*)&oW[w][1][l][0] = o1;
  *(f32x4*)&oW[w][2][l][0] = o2;
  __syncthreads();

  if (w == 0){
    float M = fmaxf(fmaxf(mW[0][q_], mW[1][q_]), fmaxf(mW[2][q_], mW[3][q_]));
    float f = __expf(mW[g][q_] - M);
    fW[g][q_] = f;
    float lf = lsW[g][q_] * f;
    lf += __shfl_xor(lf, 16);
    lf += __shfl_xor(lf, 32);
    if (g == 0) linvS[q_] = 1.f / lf;
  }
  __syncthreads();

  if (w < 3){
    float fr[4][4], li[4];
#pragma unroll
    for (int r = 0; r < 4; ++r){
      int q = g * 4 + r;
      li[r] = linvS[q];
#pragma unroll
      for (int vw = 0; vw < 4; ++vw) fr[vw][r] = fW[vw][q];
    }
    f32x4 sum = {0,0,0,0};
#pragma unroll
    for (int vw = 0; vw < 4; ++vw){
      f32x4 ov = *(const f32x4*)&oW[vw][w][l][0];
#pragma unroll
      for (int r = 0; r < 4; ++r) sum[r] += ov[r] * fr[vw][r];
    }
#pragma unroll
    for (int r = 0; r < 4; ++r){
      long bn = (long)b * 512 + qt * 16 + g * 4 + r;
      float val = sum[r] * li[r];
      if (w == 0)      wsout[bn * 384 + h * 32 + q_] = val;
      else if (w == 1) wsout[bn * 384 + h * 32 + 16 + q_] = val;
      else if (q_ < 12) wpout[bn * 160 + h * 12 + q_] = f2bf(val);
    }
  }
}

// --------- tail: 64 blocks x 16 rows; 8 waves split the 24 col-tiles (3 each)
__global__ __launch_bounds__(512) void tail_kernel(
    const unsigned short* __restrict__ wpbuf, const unsigned short* __restrict__ wpof,
    const float* __restrict__ bpo, const float* __restrict__ wso,
    const unsigned short* __restrict__ wof, const float* __restrict__ bo,
    const float* __restrict__ single, const float* __restrict__ ln_g,
    const float* __restrict__ ln_b, float* __restrict__ out)
{
  __shared__ unsigned short t1s[16][392];
  __shared__ float redS[8][16], redQ[8][16];
  int l = threadIdx.x & 63, w = threadIdx.x >> 6;   // w in 0..7
  int m0 = blockIdx.x * 16;
  int rb = (l >> 4) << 2;
  int arow = m0 + (l & 15);

  {
    short8 awp[5];
    const unsigned short* Ap = wpbuf + (long)arow * 160 + ((l >> 4) << 3);
#pragma unroll
    for (int t = 0; t < 5; ++t) awp[t] = *(const short8*)(Ap + t * 32);
#pragma unroll
    for (int c3 = 0; c3 < 3; ++c3){
      int ct = w * 3 + c3;
      f32x4 acc = {0,0,0,0};
#pragma unroll
      for (int t = 0; t < 5; ++t){
        short8 bfr = *(const short8*)(wpof + ((long)(t * 24 + ct) * 64 + l) * 8);
        acc = __builtin_amdgcn_mfma_f32_16x16x32_bf16(awp[t], bfr, acc, 0, 0, 0);
      }
      int col = ct * 16 + (l & 15);
      float bb = bpo[col];
#pragma unroll
      for (int r = 0; r < 4; ++r){
        float v = acc[r] + bb + wso[(long)(m0 + rb + r) * 384 + col];
        t1s[rb + r][col] = f2bf(v);
      }
    }
  }
  __syncthreads();

  short8 a2[12];
  {
    int lr = l & 15;
#pragma unroll
    for (int t = 0; t < 12; ++t)
      a2[t] = *(const short8*)&t1s[lr][t * 32 + ((l >> 4) << 3)];
  }
  f32x4 xa[3];
  float s1[4] = {0,0,0,0}, s2[4] = {0,0,0,0};
#pragma unroll
  for (int c3 = 0; c3 < 3; ++c3){
    int ct = w * 3 + c3;
    f32x4 acc = {0,0,0,0};
#pragma unroll
    for (int t = 0; t < 12; ++t){
      short8 bfr = *(const short8*)(wof + ((long)(t * 24 + ct) * 64 + l) * 8);
      acc = __builtin_amdgcn_mfma_f32_16x16x32_bf16(a2[t], bfr, acc, 0, 0, 0);
    }
    int col = ct * 16 + (l & 15);
    float bb = bo[col];
#pragma unroll
    for (int r = 0; r < 4; ++r){
      float v = acc[r] + bb + single[(long)(m0 + rb + r) * 384 + col];
      acc[r] = v; s1[r] += v; s2[r] += v * v;
    }
    xa[c3] = acc;
  }
#pragma unroll
  for (int off = 1; off < 16; off <<= 1){
#pragma unroll
    for (int r = 0; r < 4; ++r){
      s1[r] += __shfl_xor(s1[r], off);
      s2[r] += __shfl_xor(s2[r], off);
    }
  }
  if ((l & 15) == 0){
#pragma unroll
    for (int r = 0; r < 4; ++r){ redS[w][rb + r] = s1[r]; redQ[w][rb + r] = s2[r]; }
  }
  __syncthreads();
  float mu[4], inv[4];
#pragma unroll
  for (int r = 0; r < 4; ++r){
    float ts = 0.f, tq = 0.f;
#pragma unroll
    for (int vw = 0; vw < 8; ++vw){ ts += redS[vw][rb + r]; tq += redQ[vw][rb + r]; }
    mu[r] = ts * (1.f / 384.f);
    float var = tq * (1.f / 384.f) - mu[r] * mu[r];
    inv[r] = rsqrtf(var + 1e-5f);
  }
#pragma unroll
  for (int c3 = 0; c3 < 3; ++c3){
    int ct = w * 3 + c3;
    int col = ct * 16 + (l & 15);
    float g = ln_g[col], bt = ln_b[col];
#pragma unroll
    for (int r = 0; r < 4; ++r)
      out[(long)(m0 + rb + r) * 384 + col] = (xa[c3][r] - mu[r]) * inv[r] * g + bt;
  }
}

// -------------------------------------------------------------------- launcher
extern "C" void kernel_launch(void* const* d_in, const int* in_sizes, int n_in,
                              void* d_out, int out_size, void* d_ws, size_t ws_size,
                              hipStream_t stream)
{
  const float* single = (const float*)d_in[0];
  const float* pair   = (const float*)d_in[1];
  const float* rot    = (const float*)d_in[2];
  const float* trans  = (const float*)d_in[3];
  const float* mask   = (const float*)d_in[4];
  const float* Wq  = (const float*)d_in[5];  const float* bq  = (const float*)d_in[6];
  const float* Wk  = (const float*)d_in[7];  const float* bk  = (const float*)d_in[8];
  const float* Wv  = (const float*)d_in[9];  const float* bv  = (const float*)d_in[10];
  const float* Wpb = (const float*)d_in[11]; const float* bpb = (const float*)d_in[12];
  const float* Wqp = (const float*)d_in[13]; const float* bqp = (const float*)d_in[14];
  const float* Wkp = (const float*)d_in[15]; const float* bkp = (const float*)d_in[16];
  const float* Wvp = (const float*)d_in[17]; const float* bvp = (const float*)d_in[18];
  const float* Wo  = (const float*)d_in[19]; const float* bo  = (const float*)d_in[20];
  const float* Wpo = (const float*)d_in[21]; const float* bpo = (const float*)d_in[22];
  const float* ln_g = (const float*)d_in[23]; const float* ln_b = (const float*)d_in[24];

  char* wsb = (char*)d_ws;
  size_t off = 0;
  auto alloc = [&](size_t bytes) -> void* {
    void* p = wsb + off; off += (bytes + 255) & ~(size_t)255; return p;
  };
  unsigned short* sbf  = (unsigned short*)alloc((size_t)BN * Cc * 2);
  unsigned short* wcat = (unsigned short*)alloc((size_t)12 * CT1 * 512 * 2);
  unsigned short* wpof = (unsigned short*)alloc((size_t)5 * 24 * 512 * 2);
  unsigned short* wof  = (unsigned short*)alloc((size_t)12 * 24 * 512 * 2);
  float* bcat  = (float*)alloc(NC1 * 4);
  float* proj  = (float*)alloc((size_t)BN * NC1 * 4);
  unsigned short* biasf = (unsigned short*)alloc((size_t)Bb * Hh * Nn * Nn * 2);
  unsigned short* qfragb = (unsigned short*)alloc((size_t)786432 * 2);
  unsigned short* kfragb = (unsigned short*)alloc((size_t)786432 * 2);
  unsigned short* vfragb = (unsigned short*)alloc((size_t)589824 * 2);
  float* q2hb  = (float*)alloc((size_t)12288 * 4);
  float* k2hb  = (float*)alloc((size_t)12288 * 4);
  float* wso   = (float*)alloc((size_t)BN * 384 * 4);
  unsigned short* wpbuf = (unsigned short*)alloc((size_t)BN * 160 * 2);
  if (off > ws_size) return;

  // bias tile jobs: 1024 total; k1: [0,192), k2: [192,576), k3: [576,1024)
  k1_prep_bias<<<256 + 192, 256, 0, stream>>>(
      single, Wq, Wk, Wv, Wqp, Wkp, Wvp, bq, bk, bv, bqp, bkp, bvp, Wpo, Wo,
      pair, Wpb, bpb, sbf, wcat, bcat, wpof, wof, wpbuf, biasf);
  k2_proj_bias<<<528 + 384, 256, 0, stream>>>(
      sbf, wcat, bcat, proj, pair, Wpb, bpb, biasf);
  k3_pack_bias<<<384 + 448, 256, 0, stream>>>(
      proj, rot, trans, mask, qfragb, kfragb, vfragb, q2hb, k2hb,
      pair, Wpb, bpb, biasf);
  attn2_kernel<<<dim3(32, 12, 2), 256, 0, stream>>>(qfragb, kfragb, vfragb, biasf,
                                                    q2hb, k2hb, wso, wpbuf);
  tail_kernel<<<64, 512, 0, stream>>>(wpbuf, wpof, bpo, wso, wof, bo,
                                      single, ln_g, ln_b, (float*)d_out);
}